// Round 12
// baseline (278.507 us; speedup 1.0000x reference)
//
#include <hip/hip_runtime.h>

// ---------------------------------------------------------------------------
// MultiHeadAttention fused pipeline for MI355X (gfx950), fp16 MFMA path.
// B=2, S=2048, D=1024, H=16, Dh=64.
// d_out = [out (2*2048*1024 f32)] ++ [attn (2*16*2048*2048 f32)]
// Round 12: R10 (best: 263.7 us) with ONE change — sweep A is pipelined:
// triple-buffered K staging (3rd buffer borrows the V region), depth-2
// prefetch, exact counted vmcnt(2) waits instead of per-tile vmcnt(0)
// drains. Sweep B (256B-segment LDS-readback stores, vmcnt(8)) unchanged.
// R11's 512B-segment variant regressed (274.9) and is reverted.
// ---------------------------------------------------------------------------

using f16   = _Float16;
using f16x4 = __attribute__((ext_vector_type(4))) f16;
using f16x8 = __attribute__((ext_vector_type(8))) f16;
using f32x4 = __attribute__((ext_vector_type(4))) float;

#define MFMA16(a, b, c) __builtin_amdgcn_mfma_f32_16x16x32_f16((a), (b), (c), 0, 0, 0)

__device__ static inline float fexp2(float x) {
#if __has_builtin(__builtin_amdgcn_exp2f)
  return __builtin_amdgcn_exp2f(x);
#else
  return exp2f(x);
#endif
}

// (1/8) * log2(e): softmax scale folded into exp2 argument
#define C1 0.18033688011112042f

// counted-vmcnt barrier
#define WAIT_BARRIER(IMM)                                              \
  do {                                                                 \
    asm volatile("s_waitcnt vmcnt(" #IMM ") lgkmcnt(0)" ::: "memory"); \
    __builtin_amdgcn_s_barrier();                                      \
  } while (0)

// async global->LDS, 16 bytes per lane; lptr must be wave-uniform.
__device__ static inline void gld16(const void* gptr, void* lptr) {
  __builtin_amdgcn_global_load_lds(
      (const __attribute__((address_space(1))) void*)gptr,
      (__attribute__((address_space(3))) void*)lptr, 16, 0, 0);
}

__device__ static inline unsigned int pack2(float a, float b) {
  union { f16 h[2]; unsigned int u; } x;
  x.h[0] = (f16)a; x.h[1] = (f16)b;
  return x.u;
}

// ---------------------------------------------------------------------------
// Kernel 0: cast all fp32 inputs to fp16 into workspace.
// ---------------------------------------------------------------------------
__global__ __launch_bounds__(256) void cast_all(
    const float* __restrict__ q, const float* __restrict__ k,
    const float* __restrict__ v, const float* __restrict__ wq,
    const float* __restrict__ wk, const float* __restrict__ wv,
    const float* __restrict__ wfc, f16* __restrict__ ws) {
  int i = blockIdx.x * 256 + threadIdx.x;  // vec4 index, 0..4194303
  const float* src;
  f16* dst;
  int li;
  if (i < 3145728) {
    if (i < 1048576)      { src = q; dst = ws;            li = i; }
    else if (i < 2097152) { src = k; dst = ws + 4194304;  li = i - 1048576; }
    else                  { src = v; dst = ws + 8388608;  li = i - 2097152; }
  } else {
    int j = i - 3145728;              // 0..1048575 over 4 weights
    int wsel = j >> 18;               // 262144 vec4 per weight
    src = (wsel == 0) ? wq : (wsel == 1) ? wk : (wsel == 2) ? wv : wfc;
    dst = ws + 12582912 + wsel * 1048576;
    li = j & 262143;
  }
  float4 x = ((const float4*)src)[li];
  f16x4 y;
  y[0] = (f16)x.x; y[1] = (f16)x.y; y[2] = (f16)x.z; y[3] = (f16)x.w;
  ((f16x4*)dst)[li] = y;
}

// ---------------------------------------------------------------------------
// GEMM: C = A[4096x1024] * W[1024x1024]^T   (both stored [row][k], fp16)
// 128 x BN tile, BK=64, 4 waves (2x2), 16x16x32 MFMA, XOR-swizzled LDS,
// global_load_lds(16B) staging with pre-swizzled global source.
// MODE 3 (BN=64): C[m][n] + bias -> out fp32 [M,N]   (grid 16 x 32)
// MODE 4 (BN=128): merged QKV. grid 24 x 32.
// ---------------------------------------------------------------------------
template <int MODE, int BN>
__global__ __launch_bounds__(256) void gemm_bt(
    const f16* __restrict__ A0, const f16* __restrict__ W0,
    const float* __restrict__ bias, void* __restrict__ Cout) {
  constexpr int FJ = BN / 32;          // B-frags per wave (BN=128->4, 64->2)
  __shared__ unsigned short XA[8192];  // 128 rows x 64 k x 2B = 16 KB
  __shared__ unsigned short WB2[BN * 64];
  int tid = threadIdx.x;
  int w = tid >> 6, l = tid & 63, lq = l & 15, g = l >> 4;
  int nb3 = blockIdx.x * BN, mb = blockIdx.y * 128;
  int wsel = (MODE == 4) ? (nb3 >> 10) : 0;
  int nb = (MODE == 4) ? (nb3 & 1023) : nb3;
  const f16* A = (MODE == 4) ? A0 + (size_t)wsel * 4194304 : A0;
  const f16* W = (MODE == 4) ? W0 + (size_t)wsel * 1048576 : W0;
  bool swapR = (MODE == 4) && (wsel == 2);
  int wi = w >> 1, wj = w & 1;

  f32x4 acc[4][FJ];
#pragma unroll
  for (int i = 0; i < 4; i++)
#pragma unroll
    for (int j = 0; j < FJ; j++) acc[i][j] = (f32x4){0.f, 0.f, 0.f, 0.f};

  char* Xb = (char*)XA;
  char* Wb = (char*)WB2;
  int row = tid >> 3;                    // 0..31
  int c = (tid & 7) ^ (row & 7);         // pre-swizzled global chunk
  const f16* Asrc = A + (size_t)(mb + row) * 1024 + c * 8;
  const f16* Wsrc = W + (size_t)(nb + row) * 1024 + c * 8;

  for (int k0 = 0; k0 < 1024; k0 += 64) {
#pragma unroll
    for (int i2 = 0; i2 < 4; i2++)
      gld16(Asrc + k0 + i2 * 32 * 1024, Xb + i2 * 4096 + w * 1024);
#pragma unroll
    for (int i2 = 0; i2 < BN / 32; i2++)
      gld16(Wsrc + k0 + i2 * 32 * 1024, Wb + i2 * 4096 + w * 1024);
    __syncthreads();

    const char* at = swapR ? Wb : Xb;
    const char* bt = swapR ? Xb : Wb;

    f16x8 bfr[FJ][2];
#pragma unroll
    for (int f = 0; f < FJ; f++) {
      int r = wj * (BN / 2) + f * 16 + lq;
      int sw = (r & 7) << 4;
      bfr[f][0] = *(const f16x8*)(bt + r * 128 + ((g * 16) ^ sw));
      bfr[f][1] = *(const f16x8*)(bt + r * 128 + ((64 + g * 16) ^ sw));
    }
#pragma unroll
    for (int fi = 0; fi < 4; fi++) {
      int r = wi * 64 + fi * 16 + lq;
      int sw = (r & 7) << 4;
      f16x8 a0 = *(const f16x8*)(at + r * 128 + ((g * 16) ^ sw));
      f16x8 a1 = *(const f16x8*)(at + r * 128 + ((64 + g * 16) ^ sw));
#pragma unroll
      for (int fj = 0; fj < FJ; fj++) {
        acc[fi][fj] = MFMA16(a0, bfr[fj][0], acc[fi][fj]);
        acc[fi][fj] = MFMA16(a1, bfr[fj][1], acc[fi][fj]);
      }
    }
    __syncthreads();
  }

  // epilogue: C frag element (row = g*4+jj, col = lq)
#pragma unroll
  for (int fi = 0; fi < 4; fi++) {
#pragma unroll
    for (int fj = 0; fj < FJ; fj++) {
#pragma unroll
      for (int jj = 0; jj < 4; jj++) {
        float v = acc[fi][fj][jj];
        int iG = (swapR ? nb : mb) + wi * 64 + fi * 16 + g * 4 + jj;
        int jG = (swapR ? mb : nb) + wj * (BN / 2) + fj * 16 + lq;
        if constexpr (MODE == 3) {
          int m2 = iG, n2 = jG;
          ((float*)Cout)[(size_t)m2 * 1024 + n2] = v + bias[n2];
        } else {
          f16* dstb = (f16*)Cout + (size_t)wsel * 4194304;
          if (!swapR) {
            int m2 = iG, n2 = jG;  // m = b*2048+s, n = h*64+dh
            size_t dst = (size_t)((m2 >> 11) * 16 + (n2 >> 6)) * 131072 +
                         (size_t)(m2 & 2047) * 64 + (n2 & 63);
            dstb[dst] = (f16)v;
          } else {
            int n2 = iG, m2 = jG;  // vt[(b*1024+n)*2048 + s]
            size_t dst = (size_t)((m2 >> 11) * 1024 + n2) * 2048 + (m2 & 2047);
            dstb[dst] = (f16)v;
          }
        }
      }
    }
  }
}

// ---------------------------------------------------------------------------
// Fused attention, round 12 (= R10 + pipelined sweep A).
// 512 blocks (XCD-swizzled), 4 waves; wave w owns q rows
// qt*128 + w*32 + r, r = f*16 + lq (two fragments, ILP=2).
// Sweep A: K triple-buffered across Kl[0..2] (Kl[2] is unused-by-sweep-A
//   V LDS), depth-2 prefetch. Queue at tile-t wait: [L(t+1)2][L(t+2)2] ->
//   vmcnt(2) retires exactly L(t+1); t>=30 -> vmcnt(0).
// Sweep B: unchanged from R10. K/V double-buffered (Kl[0..1], Vl[0..1]);
//   p = exp2(s*C1)*linv packed f16 into wave-private LDS P[32][64]
//   (swizzled); PV; then STORE PHASE reads P back and writes attn as
//   8 instructions x (4 rows x 256 B contiguous). Queue per tile:
//   [L(t+1)4][S(t)8]; WAIT_BARRIER(8) retires the loads only.
// ---------------------------------------------------------------------------
__global__ __launch_bounds__(256, 2) void attn_fused(
    const f16* __restrict__ qh, const f16* __restrict__ kh,
    const f16* __restrict__ vt, float* __restrict__ attn,
    f16* __restrict__ ctx) {
  __shared__ unsigned short Kl[3][4096];  // sweep A: triple K; sweep B: [0..1]
  __shared__ unsigned short Vl[2][4096];  // sweep B V double buffer
  __shared__ unsigned short Pl[8192];     // 4 waves x [32 q][64 k]
  int tid = threadIdx.x;
  int w = tid >> 6, l = tid & 63, lq = l & 15, g = l >> 4;

  // XCD-aware swizzle: 64 blocks/XCD = 4 bh x 16 qt (bijective, 512 blocks)
  int bid = blockIdx.x;
  int xcd = bid & 7, j = bid >> 3;
  int bh = xcd * 4 + (j >> 4);
  int qt = j & 15;

  const f16* qbase = qh + (size_t)(bh * 2048 + qt * 128 + w * 32 + lq) * 64;
  f16x8 qf[2][2];
#pragma unroll
  for (int f = 0; f < 2; f++) {
    qf[f][0] = *(const f16x8*)(qbase + f * 16 * 64 + g * 8);
    qf[f][1] = *(const f16x8*)(qbase + f * 16 * 64 + 32 + g * 8);
  }
  // drain Q loads so vmcnt accounting below is exact
  asm volatile("s_waitcnt vmcnt(0)" ::: "memory");

  char* Kb = (char*)Kl;
  char* Vb = (char*)Vl;
  char* Pw = (char*)Pl + w * 4096;    // [32 q][128 B]

  int row = tid >> 3;                 // 0..31
  int c = (tid & 7) ^ (row & 7);
  const f16* ksrc = kh + (size_t)bh * 131072 + (size_t)row * 64 + c * 8;
  const f16* vsrc = vt + (size_t)bh * 131072 + (size_t)row * 2048 + c * 8;

  int swq = (lq & 7) << 4;

#define KISSUE(i, b_)                                               \
  do {                                                              \
    const f16* kp_ = ksrc + (size_t)(i) * 4096;                     \
    char* kb_ = Kb + (b_) * 8192;                                   \
    gld16(kp_, kb_ + w * 1024);                                     \
    gld16(kp_ + 2048, kb_ + 4096 + w * 1024);                       \
  } while (0)
#define VISSUE(i, b_)                                               \
  do {                                                              \
    const f16* vp_ = vsrc + (size_t)(i) * 64;                       \
    char* vb_ = Vb + (b_) * 8192;                                   \
    gld16(vp_, vb_ + w * 1024);                                     \
    gld16(vp_ + 32 * 2048, vb_ + 4096 + w * 1024);                  \
  } while (0)

  // ---------------- sweep A: row sums (triple-buffer, depth-2) -------------
  float ls[2] = {0.f, 0.f};
  KISSUE(0, 0);
  KISSUE(1, 1);                       // queue: L0(2) L1(2)
  WAIT_BARRIER(2);                    // L0 ready; L1 in flight
  {
    int bc = 0;                       // t % 3
    for (int t = 0; t < 32; t++) {
      int bn = bc + 2; if (bn >= 3) bn -= 3;     // (t+2) % 3
      if (t + 2 < 32) KISSUE(t + 2, bn);
      const char* KbC = Kb + bc * 8192;
#pragma unroll
      for (int cf = 0; cf < 4; cf++) {
        int kr = cf * 16 + lq;
        int sw = (kr & 7) << 4;
        f16x8 ka  = *(const f16x8*)(KbC + kr * 128 + ((g * 16) ^ sw));
        f16x8 kb2 = *(const f16x8*)(KbC + kr * 128 + ((64 + g * 16) ^ sw));
#pragma unroll
        for (int f = 0; f < 2; f++) {
          f32x4 s = (f32x4){0.f, 0.f, 0.f, 0.f};
          s = MFMA16(ka, qf[f][0], s);
          s = MFMA16(kb2, qf[f][1], s);
          ls[f] += fexp2(s[0] * C1) + fexp2(s[1] * C1) +
                   fexp2(s[2] * C1) + fexp2(s[3] * C1);
        }
      }
      // queue: L(t+1)(2) [L(t+2)(2) if issued] -> retire exactly L(t+1)
      if (t < 30) { WAIT_BARRIER(2); } else { WAIT_BARRIER(0); }
      bc = (bc == 2) ? 0 : bc + 1;
    }
  }
  float linv[2];
#pragma unroll
  for (int f = 0; f < 2; f++) {
    float t2 = ls[f];
    t2 += __shfl_xor(t2, 16);
    t2 += __shfl_xor(t2, 32);
    linv[f] = 1.0f / t2;
  }

  // ---------------- sweep B (R10-identical) ----------------
  f32x4 acc[2][4];
#pragma unroll
  for (int f = 0; f < 2; f++)
#pragma unroll
    for (int i = 0; i < 4; i++) acc[f][i] = (f32x4){0.f, 0.f, 0.f, 0.f};

  // store-phase constants: instruction i covers rows i*4 + (l>>4), col (l&15)*4
  int sr_sub = l >> 4;                // row-in-group 0..3
  int sc = (l & 15) * 4;              // float col within tile
  float* attnw =
      attn + ((size_t)bh * 2048 + qt * 128 + w * 32) * 2048;  // wave row base

  KISSUE(0, 0);
  VISSUE(0, 0);
  WAIT_BARRIER(0);
  for (int t = 0; t < 32; t++) {
    int kt = t * 64;
    const char* KbC = Kb + (t & 1) * 8192;
    const char* VbC = Vb + (t & 1) * 8192;
    if (t < 31) {
      KISSUE(t + 1, (t + 1) & 1);
      VISSUE(t + 1, (t + 1) & 1);
    }

    // QK^T + softmax + P pack (both q-frags share K reads)
#pragma unroll
    for (int cf = 0; cf < 4; cf++) {
      int kr = cf * 16 + lq;
      int sw = (kr & 7) << 4;
      f16x8 ka  = *(const f16x8*)(KbC + kr * 128 + ((g * 16) ^ sw));
      f16x8 kb2 = *(const f16x8*)(KbC + kr * 128 + ((64 + g * 16) ^ sw));
      int k0 = cf * 16 + g * 4;
#pragma unroll
      for (int f = 0; f < 2; f++) {
        f32x4 s = (f32x4){0.f, 0.f, 0.f, 0.f};
        s = MFMA16(ka, qf[f][0], s);
        s = MFMA16(kb2, qf[f][1], s);
        float e0 = fexp2(s[0] * C1) * linv[f];
        float e1 = fexp2(s[1] * C1) * linv[f];
        float e2 = fexp2(s[2] * C1) * linv[f];
        float e3 = fexp2(s[3] * C1) * linv[f];
        char* Pr = Pw + (f * 16 + lq) * 128;
        *(unsigned int*)(Pr + ((k0 * 2) ^ swq))       = pack2(e0, e1);
        *(unsigned int*)(Pr + (((k0 + 2) * 2) ^ swq)) = pack2(e2, e3);
      }
    }

    // PV (swapped): ctx^T[dh][q] += Vt * P^T (both frags share V reads)
    {
      f16x8 pb[2][2];
#pragma unroll
      for (int f = 0; f < 2; f++) {
        char* Pr = Pw + (f * 16 + lq) * 128;
        pb[f][0] = *(const f16x8*)(Pr + ((g * 16) ^ swq));
        pb[f][1] = *(const f16x8*)(Pr + ((64 + g * 16) ^ swq));
      }
#pragma unroll
      for (int af = 0; af < 4; af++) {
        int vr = af * 16 + lq;
        int sv = (vr & 7) << 4;
        f16x8 va0 = *(const f16x8*)(VbC + vr * 128 + ((g * 16) ^ sv));
        f16x8 va1 = *(const f16x8*)(VbC + vr * 128 + ((64 + g * 16) ^ sv));
#pragma unroll
        for (int f = 0; f < 2; f++) {
          acc[f][af] = MFMA16(va0, pb[f][0], acc[f][af]);
          acc[f][af] = MFMA16(va1, pb[f][1], acc[f][af]);
        }
      }
    }

    // STORE PHASE: read P back from LDS, write 4 rows x 256B per instruction
#pragma unroll
    for (int i = 0; i < 8; i++) {
      int r = i * 4 + sr_sub;                   // row-in-wave 0..31
      f16x4 pv = *(const f16x4*)(Pw + r * 128 + ((sc * 2) ^ ((r & 7) << 4)));
      float4 o = {(float)pv[0], (float)pv[1], (float)pv[2], (float)pv[3]};
      *(float4*)(attnw + (size_t)r * 2048 + kt + sc) = o;
    }

    // retire the 4 prefetch loads; 8 stores keep draining under next tile
    WAIT_BARRIER(8);
  }

  // ctx epilogue: transpose ctx^T -> ctx rows via wave-private LDS
#pragma unroll
  for (int f = 0; f < 2; f++) {
    char* Pr = Pw + (f * 16 + lq) * 128;
#pragma unroll
    for (int af = 0; af < 4; af++) {
#pragma unroll
      for (int jj = 0; jj < 4; jj += 2) {
        int dh0 = af * 16 + g * 4 + jj;
        *(unsigned int*)(Pr + ((dh0 * 2) ^ swq)) =
            pack2(acc[f][af][jj], acc[f][af][jj + 1]);
      }
    }
  }
  {
    int q2 = l >> 1, cc = l & 1;        // 2 lanes per q row (32 rows)
    int swr = (q2 & 7) << 4;
    int b = bh >> 4, h = bh & 15;
    f16* crow =
        ctx + ((size_t)b * 2048 + qt * 128 + w * 32 + q2) * 1024 + h * 64;
#pragma unroll
    for (int t2 = 0; t2 < 4; t2++) {
      f16x8 v2 = *(const f16x8*)(Pw + q2 * 128 + ((cc * 64 + t2 * 16) ^ swr));
      *(f16x8*)(crow + cc * 32 + t2 * 8) = v2;
    }
  }
#undef KISSUE
#undef VISSUE
}

// ---------------------------------------------------------------------------
extern "C" void kernel_launch(void* const* d_in, const int* in_sizes, int n_in,
                              void* d_out, int out_size, void* d_ws,
                              size_t ws_size, hipStream_t stream) {
  (void)in_sizes; (void)n_in; (void)out_size; (void)ws_size;
  const float* q   = (const float*)d_in[0];
  const float* k   = (const float*)d_in[1];
  const float* v   = (const float*)d_in[2];
  const float* wq  = (const float*)d_in[3];
  const float* wk  = (const float*)d_in[4];
  const float* wv  = (const float*)d_in[5];
  const float* wfc = (const float*)d_in[6];
  const float* bfc = (const float*)d_in[7];

  f16* ws = (f16*)d_ws;
  f16* qf   = ws;                     // also base for k,v (stride 4194304)
  f16* wqf  = ws + 12582912;          // base for wq,wk,wv (stride 1048576)
  f16* wfcf = ws + 15728640;
  f16* qhp  = ws + 16777216;          // base for qh,kh,vt (stride 4194304)
  f16* khp  = ws + 20971520;
  f16* vtp  = ws + 25165824;
  f16* ctxp = ws + 29360128;          // [B,S,D]

  float* outp  = (float*)d_out;
  float* attnp = outp + 4194304;

  cast_all<<<16384, 256, 0, stream>>>(q, k, v, wq, wk, wv, wfc, ws);
  gemm_bt<4, 128><<<dim3(24, 32), 256, 0, stream>>>(qf, wqf, nullptr, qhp);
  attn_fused<<<512, 256, 0, stream>>>(qhp, khp, vtp, attnp, ctxp);
  gemm_bt<3, 64><<<dim3(16, 32), 256, 0, stream>>>(ctxp, wfcf, bfc, outp);
}

// Round 14
// 260.327 us; speedup vs baseline: 1.0698x; 1.0698x over previous
//
#include <hip/hip_runtime.h>

// ---------------------------------------------------------------------------
// MultiHeadAttention fused pipeline for MI355X (gfx950), fp16 MFMA path.
// B=2, S=2048, D=1024, H=16, Dh=64.
// d_out = [out (2*2048*1024 f32)] ++ [attn (2*16*2048*2048 f32)]
// Round 14: exact revert to round 10 (best measured: 263.7 us, passed).
// R13's cast-fused GEMMs caused replay-time divergence and were slower;
// R11/R12 pipeline variants regressed. This is the proven configuration:
// R4 attention structure + 256B-segment LDS-readback attn stores.
// ---------------------------------------------------------------------------

using f16   = _Float16;
using f16x4 = __attribute__((ext_vector_type(4))) f16;
using f16x8 = __attribute__((ext_vector_type(8))) f16;
using f32x4 = __attribute__((ext_vector_type(4))) float;

#define MFMA16(a, b, c) __builtin_amdgcn_mfma_f32_16x16x32_f16((a), (b), (c), 0, 0, 0)

__device__ static inline float fexp2(float x) {
#if __has_builtin(__builtin_amdgcn_exp2f)
  return __builtin_amdgcn_exp2f(x);
#else
  return exp2f(x);
#endif
}

// (1/8) * log2(e): softmax scale folded into exp2 argument
#define C1 0.18033688011112042f

// counted-vmcnt barrier
#define WAIT_BARRIER(IMM)                                              \
  do {                                                                 \
    asm volatile("s_waitcnt vmcnt(" #IMM ") lgkmcnt(0)" ::: "memory"); \
    __builtin_amdgcn_s_barrier();                                      \
  } while (0)

// async global->LDS, 16 bytes per lane; lptr must be wave-uniform.
__device__ static inline void gld16(const void* gptr, void* lptr) {
  __builtin_amdgcn_global_load_lds(
      (const __attribute__((address_space(1))) void*)gptr,
      (__attribute__((address_space(3))) void*)lptr, 16, 0, 0);
}

__device__ static inline unsigned int pack2(float a, float b) {
  union { f16 h[2]; unsigned int u; } x;
  x.h[0] = (f16)a; x.h[1] = (f16)b;
  return x.u;
}

// ---------------------------------------------------------------------------
// Kernel 0: cast all fp32 inputs to fp16 into workspace.
// ---------------------------------------------------------------------------
__global__ __launch_bounds__(256) void cast_all(
    const float* __restrict__ q, const float* __restrict__ k,
    const float* __restrict__ v, const float* __restrict__ wq,
    const float* __restrict__ wk, const float* __restrict__ wv,
    const float* __restrict__ wfc, f16* __restrict__ ws) {
  int i = blockIdx.x * 256 + threadIdx.x;  // vec4 index, 0..4194303
  const float* src;
  f16* dst;
  int li;
  if (i < 3145728) {
    if (i < 1048576)      { src = q; dst = ws;            li = i; }
    else if (i < 2097152) { src = k; dst = ws + 4194304;  li = i - 1048576; }
    else                  { src = v; dst = ws + 8388608;  li = i - 2097152; }
  } else {
    int j = i - 3145728;              // 0..1048575 over 4 weights
    int wsel = j >> 18;               // 262144 vec4 per weight
    src = (wsel == 0) ? wq : (wsel == 1) ? wk : (wsel == 2) ? wv : wfc;
    dst = ws + 12582912 + wsel * 1048576;
    li = j & 262143;
  }
  float4 x = ((const float4*)src)[li];
  f16x4 y;
  y[0] = (f16)x.x; y[1] = (f16)x.y; y[2] = (f16)x.z; y[3] = (f16)x.w;
  ((f16x4*)dst)[li] = y;
}

// ---------------------------------------------------------------------------
// GEMM: C = A[4096x1024] * W[1024x1024]^T   (both stored [row][k], fp16)
// 128 x BN tile, BK=64, 4 waves (2x2), 16x16x32 MFMA, XOR-swizzled LDS,
// global_load_lds(16B) staging with pre-swizzled global source.
// MODE 3 (BN=64): C[m][n] + bias -> out fp32 [M,N]   (grid 16 x 32)
// MODE 4 (BN=128): merged QKV. grid 24 x 32.
// ---------------------------------------------------------------------------
template <int MODE, int BN>
__global__ __launch_bounds__(256) void gemm_bt(
    const f16* __restrict__ A0, const f16* __restrict__ W0,
    const float* __restrict__ bias, void* __restrict__ Cout) {
  constexpr int FJ = BN / 32;          // B-frags per wave (BN=128->4, 64->2)
  __shared__ unsigned short XA[8192];  // 128 rows x 64 k x 2B = 16 KB
  __shared__ unsigned short WB2[BN * 64];
  int tid = threadIdx.x;
  int w = tid >> 6, l = tid & 63, lq = l & 15, g = l >> 4;
  int nb3 = blockIdx.x * BN, mb = blockIdx.y * 128;
  int wsel = (MODE == 4) ? (nb3 >> 10) : 0;
  int nb = (MODE == 4) ? (nb3 & 1023) : nb3;
  const f16* A = (MODE == 4) ? A0 + (size_t)wsel * 4194304 : A0;
  const f16* W = (MODE == 4) ? W0 + (size_t)wsel * 1048576 : W0;
  bool swapR = (MODE == 4) && (wsel == 2);
  int wi = w >> 1, wj = w & 1;

  f32x4 acc[4][FJ];
#pragma unroll
  for (int i = 0; i < 4; i++)
#pragma unroll
    for (int j = 0; j < FJ; j++) acc[i][j] = (f32x4){0.f, 0.f, 0.f, 0.f};

  char* Xb = (char*)XA;
  char* Wb = (char*)WB2;
  int row = tid >> 3;                    // 0..31
  int c = (tid & 7) ^ (row & 7);         // pre-swizzled global chunk
  const f16* Asrc = A + (size_t)(mb + row) * 1024 + c * 8;
  const f16* Wsrc = W + (size_t)(nb + row) * 1024 + c * 8;

  for (int k0 = 0; k0 < 1024; k0 += 64) {
#pragma unroll
    for (int i2 = 0; i2 < 4; i2++)
      gld16(Asrc + k0 + i2 * 32 * 1024, Xb + i2 * 4096 + w * 1024);
#pragma unroll
    for (int i2 = 0; i2 < BN / 32; i2++)
      gld16(Wsrc + k0 + i2 * 32 * 1024, Wb + i2 * 4096 + w * 1024);
    __syncthreads();

    const char* at = swapR ? Wb : Xb;
    const char* bt = swapR ? Xb : Wb;

    f16x8 bfr[FJ][2];
#pragma unroll
    for (int f = 0; f < FJ; f++) {
      int r = wj * (BN / 2) + f * 16 + lq;
      int sw = (r & 7) << 4;
      bfr[f][0] = *(const f16x8*)(bt + r * 128 + ((g * 16) ^ sw));
      bfr[f][1] = *(const f16x8*)(bt + r * 128 + ((64 + g * 16) ^ sw));
    }
#pragma unroll
    for (int fi = 0; fi < 4; fi++) {
      int r = wi * 64 + fi * 16 + lq;
      int sw = (r & 7) << 4;
      f16x8 a0 = *(const f16x8*)(at + r * 128 + ((g * 16) ^ sw));
      f16x8 a1 = *(const f16x8*)(at + r * 128 + ((64 + g * 16) ^ sw));
#pragma unroll
      for (int fj = 0; fj < FJ; fj++) {
        acc[fi][fj] = MFMA16(a0, bfr[fj][0], acc[fi][fj]);
        acc[fi][fj] = MFMA16(a1, bfr[fj][1], acc[fi][fj]);
      }
    }
    __syncthreads();
  }

  // epilogue: C frag element (row = g*4+jj, col = lq)
#pragma unroll
  for (int fi = 0; fi < 4; fi++) {
#pragma unroll
    for (int fj = 0; fj < FJ; fj++) {
#pragma unroll
      for (int jj = 0; jj < 4; jj++) {
        float v = acc[fi][fj][jj];
        int iG = (swapR ? nb : mb) + wi * 64 + fi * 16 + g * 4 + jj;
        int jG = (swapR ? mb : nb) + wj * (BN / 2) + fj * 16 + lq;
        if constexpr (MODE == 3) {
          int m2 = iG, n2 = jG;
          ((float*)Cout)[(size_t)m2 * 1024 + n2] = v + bias[n2];
        } else {
          f16* dstb = (f16*)Cout + (size_t)wsel * 4194304;
          if (!swapR) {
            int m2 = iG, n2 = jG;  // m = b*2048+s, n = h*64+dh
            size_t dst = (size_t)((m2 >> 11) * 16 + (n2 >> 6)) * 131072 +
                         (size_t)(m2 & 2047) * 64 + (n2 & 63);
            dstb[dst] = (f16)v;
          } else {
            int n2 = iG, m2 = jG;  // vt[(b*1024+n)*2048 + s]
            size_t dst = (size_t)((m2 >> 11) * 1024 + n2) * 2048 + (m2 & 2047);
            dstb[dst] = (f16)v;
          }
        }
      }
    }
  }
}

// ---------------------------------------------------------------------------
// Fused attention, round 10 config (= R4 + dense attn store phase).
// 512 blocks (XCD-swizzled), 4 waves; wave w owns q rows
// qt*128 + w*32 + r, r = f*16 + lq (two fragments, ILP=2).
// Sweep A: staged-K QK^T + exp2 row-sum, fixed max = 0; WB(0) per tile.
// Sweep B: staged K+V (double-buffered); p = exp2(s*C1)*linv packed f16 into
//   wave-private LDS P[32][64] (swizzled); PV; then STORE PHASE reads P back
//   (ds_read) and writes attn as 8 instructions of 4 rows x 256 B
//   contiguous segments (was 16 rows x 64 B direct).
// Queue per tile: [L(t+1) 4][S(t) 8]; WAIT_BARRIER(8) retires the loads.
// ---------------------------------------------------------------------------
__global__ __launch_bounds__(256, 2) void attn_fused(
    const f16* __restrict__ qh, const f16* __restrict__ kh,
    const f16* __restrict__ vt, float* __restrict__ attn,
    f16* __restrict__ ctx) {
  __shared__ unsigned short Kl0[4096], Kl1[4096];  // [64 k][64 dh] swz, 8 KB ea
  __shared__ unsigned short Vl0[4096], Vl1[4096];  // [64 dh][64 k] swz
  __shared__ unsigned short Pl[8192];              // 4 waves x [32 q][64 k]
  int tid = threadIdx.x;
  int w = tid >> 6, l = tid & 63, lq = l & 15, g = l >> 4;

  // XCD-aware swizzle: 64 blocks/XCD = 4 bh x 16 qt (bijective, 512 blocks)
  int bid = blockIdx.x;
  int xcd = bid & 7, j = bid >> 3;
  int bh = xcd * 4 + (j >> 4);
  int qt = j & 15;

  const f16* qbase = qh + (size_t)(bh * 2048 + qt * 128 + w * 32 + lq) * 64;
  f16x8 qf[2][2];
#pragma unroll
  for (int f = 0; f < 2; f++) {
    qf[f][0] = *(const f16x8*)(qbase + f * 16 * 64 + g * 8);
    qf[f][1] = *(const f16x8*)(qbase + f * 16 * 64 + 32 + g * 8);
  }

  char* Kb0 = (char*)Kl0;
  char* Kb1 = (char*)Kl1;
  char* Vb0 = (char*)Vl0;
  char* Vb1 = (char*)Vl1;
  char* Pw  = (char*)Pl + w * 4096;   // [32 q][128 B]

  int row = tid >> 3;                 // 0..31
  int c = (tid & 7) ^ (row & 7);
  const f16* ksrc = kh + (size_t)bh * 131072 + (size_t)row * 64 + c * 8;
  const f16* vsrc = vt + (size_t)bh * 131072 + (size_t)row * 2048 + c * 8;

  int swq = (lq & 7) << 4;

  // ---------------- sweep A: row sums ----------------
  float ls[2] = {0.f, 0.f};
  gld16(ksrc,           Kb0 + w * 1024);
  gld16(ksrc + 32 * 64, Kb0 + 4096 + w * 1024);
  WAIT_BARRIER(0);
  for (int t = 0; t < 32; t++) {
    char* KbC = (t & 1) ? Kb1 : Kb0;
    char* KbN = (t & 1) ? Kb0 : Kb1;
    if (t < 31) {
      const f16* kp = ksrc + (size_t)(t + 1) * 4096;
      gld16(kp,           KbN + w * 1024);
      gld16(kp + 32 * 64, KbN + 4096 + w * 1024);
    }
#pragma unroll
    for (int cf = 0; cf < 4; cf++) {
      int kr = cf * 16 + lq;
      int sw = (kr & 7) << 4;
      f16x8 ka  = *(const f16x8*)(KbC + kr * 128 + ((g * 16) ^ sw));
      f16x8 kb2 = *(const f16x8*)(KbC + kr * 128 + ((64 + g * 16) ^ sw));
#pragma unroll
      for (int f = 0; f < 2; f++) {
        f32x4 s = (f32x4){0.f, 0.f, 0.f, 0.f};
        s = MFMA16(ka, qf[f][0], s);
        s = MFMA16(kb2, qf[f][1], s);
        ls[f] += fexp2(s[0] * C1) + fexp2(s[1] * C1) +
                 fexp2(s[2] * C1) + fexp2(s[3] * C1);
      }
    }
    WAIT_BARRIER(0);
  }
  float linv[2];
#pragma unroll
  for (int f = 0; f < 2; f++) {
    float t = ls[f];
    t += __shfl_xor(t, 16);
    t += __shfl_xor(t, 32);
    linv[f] = 1.0f / t;
  }

  // ---------------- sweep B ----------------
  f32x4 acc[2][4];
#pragma unroll
  for (int f = 0; f < 2; f++)
#pragma unroll
    for (int i = 0; i < 4; i++) acc[f][i] = (f32x4){0.f, 0.f, 0.f, 0.f};

  // store-phase constants: instruction i covers rows i*4 + (l>>4), col (l&15)*4
  int sr_sub = l >> 4;                // row-in-group 0..3
  int sc = (l & 15) * 4;              // float col within tile
  float* attnw =
      attn + ((size_t)bh * 2048 + qt * 128 + w * 32) * 2048;  // wave row base

  gld16(ksrc,             Kb0 + w * 1024);
  gld16(ksrc + 32 * 64,   Kb0 + 4096 + w * 1024);
  gld16(vsrc,             Vb0 + w * 1024);
  gld16(vsrc + 32 * 2048, Vb0 + 4096 + w * 1024);
  WAIT_BARRIER(0);
  for (int t = 0; t < 32; t++) {
    int kt = t * 64;
    char* KbC = (t & 1) ? Kb1 : Kb0;
    char* KbN = (t & 1) ? Kb0 : Kb1;
    char* VbC = (t & 1) ? Vb1 : Vb0;
    char* VbN = (t & 1) ? Vb0 : Vb1;
    if (t < 31) {
      const f16* kp = ksrc + (size_t)(t + 1) * 4096;
      const f16* vp = vsrc + (size_t)(t + 1) * 64;
      gld16(kp,             KbN + w * 1024);
      gld16(kp + 32 * 64,   KbN + 4096 + w * 1024);
      gld16(vp,             VbN + w * 1024);
      gld16(vp + 32 * 2048, VbN + 4096 + w * 1024);
    }

    // QK^T + softmax + P pack (both q-frags share K reads)
#pragma unroll
    for (int cf = 0; cf < 4; cf++) {
      int kr = cf * 16 + lq;
      int sw = (kr & 7) << 4;
      f16x8 ka  = *(const f16x8*)(KbC + kr * 128 + ((g * 16) ^ sw));
      f16x8 kb2 = *(const f16x8*)(KbC + kr * 128 + ((64 + g * 16) ^ sw));
      int k0 = cf * 16 + g * 4;
#pragma unroll
      for (int f = 0; f < 2; f++) {
        f32x4 s = (f32x4){0.f, 0.f, 0.f, 0.f};
        s = MFMA16(ka, qf[f][0], s);
        s = MFMA16(kb2, qf[f][1], s);
        float e0 = fexp2(s[0] * C1) * linv[f];
        float e1 = fexp2(s[1] * C1) * linv[f];
        float e2 = fexp2(s[2] * C1) * linv[f];
        float e3 = fexp2(s[3] * C1) * linv[f];
        char* Pr = Pw + (f * 16 + lq) * 128;
        *(unsigned int*)(Pr + ((k0 * 2) ^ swq))       = pack2(e0, e1);
        *(unsigned int*)(Pr + (((k0 + 2) * 2) ^ swq)) = pack2(e2, e3);
      }
    }

    // PV (swapped): ctx^T[dh][q] += Vt * P^T (both frags share V reads)
    {
      f16x8 pb[2][2];
#pragma unroll
      for (int f = 0; f < 2; f++) {
        char* Pr = Pw + (f * 16 + lq) * 128;
        pb[f][0] = *(const f16x8*)(Pr + ((g * 16) ^ swq));
        pb[f][1] = *(const f16x8*)(Pr + ((64 + g * 16) ^ swq));
      }
#pragma unroll
      for (int af = 0; af < 4; af++) {
        int vr = af * 16 + lq;
        int sv = (vr & 7) << 4;
        f16x8 va0 = *(const f16x8*)(VbC + vr * 128 + ((g * 16) ^ sv));
        f16x8 va1 = *(const f16x8*)(VbC + vr * 128 + ((64 + g * 16) ^ sv));
#pragma unroll
        for (int f = 0; f < 2; f++) {
          acc[f][af] = MFMA16(va0, pb[f][0], acc[f][af]);
          acc[f][af] = MFMA16(va1, pb[f][1], acc[f][af]);
        }
      }
    }

    // STORE PHASE: read P back from LDS, write 4 rows x 256B per instruction
#pragma unroll
    for (int i = 0; i < 8; i++) {
      int r = i * 4 + sr_sub;                   // row-in-wave 0..31
      f16x4 pv = *(const f16x4*)(Pw + r * 128 + ((sc * 2) ^ ((r & 7) << 4)));
      float4 o = {(float)pv[0], (float)pv[1], (float)pv[2], (float)pv[3]};
      *(float4*)(attnw + (size_t)r * 2048 + kt + sc) = o;
    }

    // retire the 4 prefetch loads; 8 stores keep draining under next tile
    WAIT_BARRIER(8);
  }

  // ctx epilogue: transpose ctx^T -> ctx rows via wave-private LDS
#pragma unroll
  for (int f = 0; f < 2; f++) {
    char* Pr = Pw + (f * 16 + lq) * 128;
#pragma unroll
    for (int af = 0; af < 4; af++) {
#pragma unroll
      for (int jj = 0; jj < 4; jj += 2) {
        int dh0 = af * 16 + g * 4 + jj;
        *(unsigned int*)(Pr + ((dh0 * 2) ^ swq)) =
            pack2(acc[f][af][jj], acc[f][af][jj + 1]);
      }
    }
  }
  {
    int q2 = l >> 1, cc = l & 1;        // 2 lanes per q row (32 rows)
    int swr = (q2 & 7) << 4;
    int b = bh >> 4, h = bh & 15;
    f16* crow =
        ctx + ((size_t)b * 2048 + qt * 128 + w * 32 + q2) * 1024 + h * 64;
#pragma unroll
    for (int t2 = 0; t2 < 4; t2++) {
      f16x8 v2 = *(const f16x8*)(Pw + q2 * 128 + ((cc * 64 + t2 * 16) ^ swr));
      *(f16x8*)(crow + cc * 32 + t2 * 8) = v2;
    }
  }
}

// ---------------------------------------------------------------------------
extern "C" void kernel_launch(void* const* d_in, const int* in_sizes, int n_in,
                              void* d_out, int out_size, void* d_ws,
                              size_t ws_size, hipStream_t stream) {
  (void)in_sizes; (void)n_in; (void)out_size; (void)ws_size;
  const float* q   = (const float*)d_in[0];
  const float* k   = (const float*)d_in[1];
  const float* v   = (const float*)d_in[2];
  const float* wq  = (const float*)d_in[3];
  const float* wk  = (const float*)d_in[4];
  const float* wv  = (const float*)d_in[5];
  const float* wfc = (const float*)d_in[6];
  const float* bfc = (const float*)d_in[7];

  f16* ws = (f16*)d_ws;
  f16* qf   = ws;                     // also base for k,v (stride 4194304)
  f16* wqf  = ws + 12582912;          // base for wq,wk,wv (stride 1048576)
  f16* wfcf = ws + 15728640;
  f16* qhp  = ws + 16777216;          // base for qh,kh,vt (stride 4194304)
  f16* khp  = ws + 20971520;
  f16* vtp  = ws + 25165824;
  f16* ctxp = ws + 29360128;          // [B,S,D]

  float* outp  = (float*)d_out;
  float* attnp = outp + 4194304;

  cast_all<<<16384, 256, 0, stream>>>(q, k, v, wq, wk, wv, wfc, ws);
  gemm_bt<4, 128><<<dim3(24, 32), 256, 0, stream>>>(qf, wqf, nullptr, qhp);
  attn_fused<<<512, 256, 0, stream>>>(qhp, khp, vtp, attnp, ctxp);
  gemm_bt<3, 64><<<dim3(16, 32), 256, 0, stream>>>(ctxp, wfcf, bfc, outp);
}